// Round 1
// baseline (3240.622 us; speedup 1.0000x reference)
//
#include <hip/hip_runtime.h>
#include <math.h>

#define T_PER_BLOCK 16
#define N_EXPERTS   256
#define HDIM        7168
#define NGROUP      8
#define EPG         32   // experts per group
#define TOPKG       4
#define TOPK        8
#define RSF         2.5

// Fused MoE gate, full fp64 compute (correctness probe).
// Block: 256 threads = 256 experts; 16 tokens per block.
__global__ __launch_bounds__(256) void moe_gate_f64(
    const float* __restrict__ x,     // [T, 7168] fp32
    const float* __restrict__ wk,    // [7168, 256] fp32
    const float* __restrict__ bias,  // [256] fp32
    float* __restrict__ out,         // [T*8 idx-as-float][T*8 weights]
    int T)
{
    // +1 double pad per row breaks the stride-256 bank pattern for the
    // per-token serial selection phase.
    __shared__ double sc[T_PER_BLOCK][N_EXPERTS + 1];

    const int  e  = threadIdx.x;
    const long t0 = (long)blockIdx.x * T_PER_BLOCK;
    const float* xb = x + t0 * HDIM;

    double acc[T_PER_BLOCK];
#pragma unroll
    for (int t = 0; t < T_PER_BLOCK; ++t) acc[t] = 0.0;

    // K loop, unrolled by 4. x loads are wave-uniform (scalarizable);
    // wk loads are coalesced (lane = expert, contiguous).
    for (int k = 0; k < HDIM; k += 4) {
        double kv0 = (double)wk[(long)(k + 0) * N_EXPERTS + e];
        double kv1 = (double)wk[(long)(k + 1) * N_EXPERTS + e];
        double kv2 = (double)wk[(long)(k + 2) * N_EXPERTS + e];
        double kv3 = (double)wk[(long)(k + 3) * N_EXPERTS + e];
#pragma unroll
        for (int t = 0; t < T_PER_BLOCK; ++t) {
            const float* xr = xb + (long)t * HDIM + k;
            double a = acc[t];
            a = fma((double)xr[0], kv0, a);
            a = fma((double)xr[1], kv1, a);
            a = fma((double)xr[2], kv2, a);
            a = fma((double)xr[3], kv3, a);
            acc[t] = a;
        }
    }

    // sigmoid + bias in fp64, stash scores_for_choice in LDS
    const double b = (double)bias[e];
#pragma unroll
    for (int t = 0; t < T_PER_BLOCK; ++t) {
        double s = 1.0 / (1.0 + exp(-acc[t]));
        sc[t][e] = s + b;
    }
    __syncthreads();

    // Serial per-token selection: threads 0..15, one token each.
    if (threadIdx.x < T_PER_BLOCK) {
        const int t = threadIdx.x;

        // per-group sum of top-2
        double gsum[NGROUP];
        for (int g = 0; g < NGROUP; ++g) {
            double m1 = -1e300, m2 = -1e300;
            for (int j = 0; j < EPG; ++j) {
                double v = sc[t][g * EPG + j];
                if (v > m1) { m2 = m1; m1 = v; }
                else if (v > m2) { m2 = v; }
            }
            gsum[g] = m1 + m2;
        }

        // top-4 groups (strict > == lowest index on ties, matches lax.top_k)
        bool gsel[NGROUP];
        for (int g = 0; g < NGROUP; ++g) gsel[g] = false;
        for (int r = 0; r < TOPKG; ++r) {
            double best = -1e300; int bi = 0;
            for (int g = 0; g < NGROUP; ++g)
                if (!gsel[g] && gsum[g] > best) { best = gsum[g]; bi = g; }
            gsel[bi] = true;
        }

        // mask out unselected groups with exact 0.0 (as the reference does)
        for (int e2 = 0; e2 < N_EXPERTS; ++e2)
            if (!gsel[e2 / EPG]) sc[t][e2] = 0.0;

        // top-8 experts, stable (lowest index first among equals)
        int    id[TOPK];
        double wv[TOPK];
        double wsum = 0.0;
        for (int r = 0; r < TOPK; ++r) {
            double best = -1e300; int bi = 0;
            for (int e2 = 0; e2 < N_EXPERTS; ++e2) {
                double v = sc[t][e2];
                if (v > best) { best = v; bi = e2; }
            }
            sc[t][bi] = -1e300;
            id[r] = bi; wv[r] = best; wsum += best;
        }

        const double inv = RSF / (wsum + 1e-20);
        const long base  = (t0 + t) * TOPK;
        const long wbase = (long)T * TOPK + base;
        for (int r = 0; r < TOPK; ++r) {
            out[base + r]  = (float)id[r];
            out[wbase + r] = (float)(wv[r] * inv);
        }
    }
}

extern "C" void kernel_launch(void* const* d_in, const int* in_sizes, int n_in,
                              void* d_out, int out_size, void* d_ws, size_t ws_size,
                              hipStream_t stream) {
    const float* x    = (const float*)d_in[0];
    const float* wk   = (const float*)d_in[1];
    const float* bias = (const float*)d_in[2];
    float* out = (float*)d_out;

    const int T  = in_sizes[0] / HDIM;          // 16384
    const int nb = (T + T_PER_BLOCK - 1) / T_PER_BLOCK;

    hipLaunchKernelGGL(moe_gate_f64, dim3(nb), dim3(256), 0, stream,
                       x, wk, bias, out, T);
}

// Round 2
// 1642.570 us; speedup vs baseline: 1.9729x; 1.9729x over previous
//
#include <hip/hip_runtime.h>
#include <math.h>

#define HDIM   7168
#define NEXP   256
#define NGROUP 8
#define EPG    32
#define TOPKG  4
#define TOPK   8
#define RSF    2.5

#define BM     64
#define BK     64
#define NCH    (HDIM / BK)      // 112
#define THREADS 512

#define TAU    5e-6f            // expert-margin refine threshold (~30 sigma)
#define TAUG   1e-5f            // group-margin refine threshold

typedef _Float16 f16x8 __attribute__((ext_vector_type(8)));
typedef float    f32x16 __attribute__((ext_vector_type(16)));

// ws layout (bytes):
//   [0]        int refine counter
//   [256]      int refine token list (16384 entries, 64 KB)
//   [66048]    khi image, 112 chunks x 32768 B  (f16, [chunk][col][u^swz][8])
//   [3736064]  klo image, same size
#define WS_CNT_OFF  0
#define WS_LIST_OFF 256
#define WS_KHI_OFF  66048
#define WS_KLO_OFF  (66048 + 3670016)

__device__ __forceinline__ void gload_lds16(const void* g, void* l) {
    __builtin_amdgcn_global_load_lds(
        (const __attribute__((address_space(1))) unsigned int*)g,
        (__attribute__((address_space(3))) unsigned int*)(unsigned long long)(uintptr_t)l,
        16, 0, 0);
}

// ---------------- prep: split+transpose+swizzle gate matrix, zero counter ---
__global__ __launch_bounds__(256) void moe_prep(
    const float* __restrict__ wk, char* __restrict__ khi, char* __restrict__ klo,
    int* __restrict__ cnt)
{
    if (blockIdx.x == 0 && threadIdx.x == 0) *cnt = 0;
    const int c   = blockIdx.x;    // chunk 0..111
    const int col = threadIdx.x;   // 0..255
    const long cb = (long)c * 32768 + (long)col * 128;
#pragma unroll
    for (int u = 0; u < 8; ++u) {
        f16x8 h8, l8;
#pragma unroll
        for (int i = 0; i < 8; ++i) {
            float v = wk[(long)(c * 64 + u * 8 + i) * NEXP + col];
            _Float16 h = (_Float16)v;
            float r = (v - (float)h) * 2048.0f;
            h8[i] = h;
            l8[i] = (_Float16)r;
        }
        const int uo = (u ^ (col & 7)) << 4;
        *(f16x8*)(khi + cb + uo) = h8;
        *(f16x8*)(klo + cb + uo) = l8;
    }
}

// ---------------- main: split-f16 MFMA GEMM + fused gating ------------------
__global__ __launch_bounds__(THREADS, 1) void moe_main(
    const float* __restrict__ x, const char* __restrict__ khi,
    const char* __restrict__ klo, const float* __restrict__ bias,
    float* __restrict__ out, int* __restrict__ cnt, int* __restrict__ list, int T)
{
    __shared__ __align__(16) char smem[81920];
    char* xs_hi = smem;              // [64][128B]  8 KB
    char* xs_lo = smem + 8192;       // 8 KB
    char* ks_hi = smem + 16384;      // [256][128B] 32 KB
    char* ks_lo = smem + 49152;      // 32 KB

    const int tid  = threadIdx.x;
    const int w    = tid >> 6;
    const int l    = tid & 63;
    const int l31  = l & 31;
    const int half = l >> 5;
    const int e7   = l31 & 7;
    const int mg   = w & 1;          // M wave group (rows mg*32..)
    const int ng   = w >> 1;         // N wave group (cols ng*64..)
    const long t0  = (long)blockIdx.x * BM;

    // x staging assignment: thread -> (row, 8-float k segment)
    const int srow = tid >> 3;           // 0..63
    const int sk8  = (tid & 7) * 8;      // 0..56
    const float* xg = x + (t0 + srow) * HDIM + sk8;
    const int xoff = srow * 128 + ((((sk8 >> 3)) ^ (srow & 7)) << 4);

    f32x16 accm0, accc0, accm1, accc1;
#pragma unroll
    for (int i = 0; i < 16; ++i) { accm0[i] = 0.f; accc0[i] = 0.f; accm1[i] = 0.f; accc1[i] = 0.f; }

    const int arow_off = (mg * 32 + l31) * 128;
    const int bc0      = (ng * 64 + l31) * 128;

    // ---- prologue: stage chunk 0
    {
        float4 p0 = *(const float4*)(xg);
        float4 p1 = *(const float4*)(xg + 4);
        float vv[8] = {p0.x, p0.y, p0.z, p0.w, p1.x, p1.y, p1.z, p1.w};
        f16x8 h8, l8;
#pragma unroll
        for (int i = 0; i < 8; ++i) {
            _Float16 h = (_Float16)vv[i];
            h8[i] = h;
            l8[i] = (_Float16)((vv[i] - (float)h) * 2048.0f);
        }
        *(f16x8*)(xs_hi + xoff) = h8;
        *(f16x8*)(xs_lo + xoff) = l8;
#pragma unroll
        for (int j = 0; j < 4; ++j) {
            const int seg = (w * 4 + j) * 1024;
            gload_lds16(khi + seg + l * 16, ks_hi + seg);
            gload_lds16(klo + seg + l * 16, ks_lo + seg);
        }
    }

    for (int c = 0; c < NCH; ++c) {
        __syncthreads();   // chunk c staged (barrier drains vm/lgkm)

        float4 p0, p1;
        const bool pf = (c + 1 < NCH);
        if (pf) {
            const float* xp = xg + (long)(c + 1) * BK;
            p0 = *(const float4*)(xp);
            p1 = *(const float4*)(xp + 4);
        }

#pragma unroll
        for (int s = 0; s < 4; ++s) {
            const int uo = (((s * 2 + half) ^ e7) << 4);
            f16x8 ah  = *(const f16x8*)(xs_hi + arow_off + uo);
            f16x8 al  = *(const f16x8*)(xs_lo + arow_off + uo);
            f16x8 bh0 = *(const f16x8*)(ks_hi + bc0 + uo);
            f16x8 bl0 = *(const f16x8*)(ks_lo + bc0 + uo);
            f16x8 bh1 = *(const f16x8*)(ks_hi + bc0 + 4096 + uo);
            f16x8 bl1 = *(const f16x8*)(ks_lo + bc0 + 4096 + uo);
            accm0 = __builtin_amdgcn_mfma_f32_32x32x16_f16(ah, bh0, accm0, 0, 0, 0);
            accc0 = __builtin_amdgcn_mfma_f32_32x32x16_f16(ah, bl0, accc0, 0, 0, 0);
            accc0 = __builtin_amdgcn_mfma_f32_32x32x16_f16(al, bh0, accc0, 0, 0, 0);
            accm1 = __builtin_amdgcn_mfma_f32_32x32x16_f16(ah, bh1, accm1, 0, 0, 0);
            accc1 = __builtin_amdgcn_mfma_f32_32x32x16_f16(ah, bl1, accc1, 0, 0, 0);
            accc1 = __builtin_amdgcn_mfma_f32_32x32x16_f16(al, bh1, accc1, 0, 0, 0);
        }

        __syncthreads();   // everyone done reading chunk c

        if (pf) {
            float vv[8] = {p0.x, p0.y, p0.z, p0.w, p1.x, p1.y, p1.z, p1.w};
            f16x8 h8, l8;
#pragma unroll
            for (int i = 0; i < 8; ++i) {
                _Float16 h = (_Float16)vv[i];
                h8[i] = h;
                l8[i] = (_Float16)((vv[i] - (float)h) * 2048.0f);
            }
            *(f16x8*)(xs_hi + xoff) = h8;
            *(f16x8*)(xs_lo + xoff) = l8;
            const long cb = (long)(c + 1) * 32768;
#pragma unroll
            for (int j = 0; j < 4; ++j) {
                const int seg = (w * 4 + j) * 1024;
                gload_lds16(khi + cb + seg + l * 16, ks_hi + seg);
                gload_lds16(klo + cb + seg + l * 16, ks_lo + seg);
            }
        }
    }
    // last loop iteration ended with a barrier: LDS free to reuse as scores

    float* sc = (float*)smem;        // [64][257] f32
    const float invs = 1.0f / 2048.0f;
    const float b0 = bias[ng * 64 + l31];
    const float b1 = bias[ng * 64 + 32 + l31];
#pragma unroll
    for (int r = 0; r < 16; ++r) {
        const int row = mg * 32 + (r & 3) + 8 * (r >> 2) + 4 * half;
        float lg0 = accm0[r] + accc0[r] * invs;
        float lg1 = accm1[r] + accc1[r] * invs;
        sc[row * 257 + (ng * 64 + l31)]      = 1.0f / (1.0f + expf(-lg0)) + b0;
        sc[row * 257 + (ng * 64 + 32 + l31)] = 1.0f / (1.0f + expf(-lg1)) + b1;
    }
    __syncthreads();

    // ---- fused selection: thread t handles token t (wave 0 only)
    if (tid < BM) {
        float* row = sc + tid * 257;

        float gsum[NGROUP];
#pragma unroll
        for (int g = 0; g < NGROUP; ++g) {
            float m1 = -1e30f, m2 = -1e30f;
            for (int j = 0; j < EPG; ++j) {
                float v = row[g * EPG + j];
                if (v > m1) { m2 = m1; m1 = v; }
                else if (v > m2) { m2 = v; }
            }
            gsum[g] = m1 + m2;
        }

        bool gsel[NGROUP];
#pragma unroll
        for (int g = 0; g < NGROUP; ++g) gsel[g] = false;
        float g4 = 0.0f;
        for (int r = 0; r < TOPKG; ++r) {
            float best = -1e30f; int bi = 0;
            for (int g = 0; g < NGROUP; ++g)
                if (!gsel[g] && gsum[g] > best) { best = gsum[g]; bi = g; }
            gsel[bi] = true; g4 = best;
        }
        float g5 = -1e30f;
        for (int g = 0; g < NGROUP; ++g)
            if (!gsel[g] && gsum[g] > g5) g5 = gsum[g];
        const float margin_g = g4 - g5;

        for (int e = 0; e < NEXP; ++e)
            if (!gsel[e >> 5]) row[e] = 0.0f;

        int   id[TOPK];
        float wv[TOPK];
        float wsum = 0.0f;
        for (int r = 0; r < TOPK; ++r) {
            float best = -1e30f; int bi = 0;
            for (int e = 0; e < NEXP; ++e) {
                float v = row[e];
                if (v > best) { best = v; bi = e; }
            }
            row[bi] = -1e30f;
            id[r] = bi; wv[r] = best; wsum += best;
        }
        float s9 = -1e30f;
        for (int e = 0; e < NEXP; ++e)
            if (row[e] > s9) s9 = row[e];

        float mmin = wv[TOPK - 1] - s9;
#pragma unroll
        for (int r = 0; r < TOPK - 1; ++r) {
            float d = wv[r] - wv[r + 1];
            if (d < mmin) mmin = d;
        }

        const float inv = 2.5f / (wsum + 1e-20f);
        const long base  = (t0 + tid) * TOPK;
        const long wbase = (long)T * TOPK + base;
#pragma unroll
        for (int r = 0; r < TOPK; ++r) {
            out[base + r]  = (float)id[r];
            out[wbase + r] = wv[r] * inv;
        }

        if (mmin < TAU || margin_g < TAUG) {
            int p = atomicAdd(cnt, 1);
            if (p < T) list[p] = (int)(t0 + tid);
        }
    }
}

// ---------------- refine: exact fp64 recompute of flagged tokens ------------
__global__ __launch_bounds__(256) void moe_refine(
    const float* __restrict__ x, const float* __restrict__ wk,
    const float* __restrict__ bias, float* __restrict__ out,
    const int* __restrict__ cnt, const int* __restrict__ list, int T)
{
    __shared__ double sd[NEXP + 1];
    int n = *cnt;
    if (n > T) n = T;
    const int e = threadIdx.x;

    for (int i = blockIdx.x; i < n; i += gridDim.x) {
        const int t = list[i];
        const float* xr = x + (long)t * HDIM;
        double acc = 0.0;
#pragma unroll 4
        for (int k = 0; k < HDIM; ++k)
            acc = fma((double)xr[k], (double)wk[(long)k * NEXP + e], acc);
        sd[e] = 1.0 / (1.0 + exp(-acc)) + (double)bias[e];
        __syncthreads();

        if (e == 0) {
            double gsum[NGROUP];
            for (int g = 0; g < NGROUP; ++g) {
                double m1 = -1e300, m2 = -1e300;
                for (int j = 0; j < EPG; ++j) {
                    double v = sd[g * EPG + j];
                    if (v > m1) { m2 = m1; m1 = v; }
                    else if (v > m2) { m2 = v; }
                }
                gsum[g] = m1 + m2;
            }
            bool gsel[NGROUP];
            for (int g = 0; g < NGROUP; ++g) gsel[g] = false;
            for (int r = 0; r < TOPKG; ++r) {
                double best = -1e300; int bi = 0;
                for (int g = 0; g < NGROUP; ++g)
                    if (!gsel[g] && gsum[g] > best) { best = gsum[g]; bi = g; }
                gsel[bi] = true;
            }
            for (int e2 = 0; e2 < NEXP; ++e2)
                if (!gsel[e2 >> 5]) sd[e2] = 0.0;

            int id[TOPK]; double wv[TOPK]; double wsum = 0.0;
            for (int r = 0; r < TOPK; ++r) {
                double best = -1e300; int bi = 0;
                for (int e2 = 0; e2 < NEXP; ++e2) {
                    double v = sd[e2];
                    if (v > best) { best = v; bi = e2; }
                }
                sd[bi] = -1e300;
                id[r] = bi; wv[r] = best; wsum += best;
            }
            const double inv = RSF / (wsum + 1e-20);
            const long base  = (long)t * TOPK;
            const long wbase = (long)T * TOPK + base;
            for (int r = 0; r < TOPK; ++r) {
                out[base + r]  = (float)id[r];
                out[wbase + r] = (float)(wv[r] * inv);
            }
        }
        __syncthreads();
    }
}

extern "C" void kernel_launch(void* const* d_in, const int* in_sizes, int n_in,
                              void* d_out, int out_size, void* d_ws, size_t ws_size,
                              hipStream_t stream) {
    const float* x    = (const float*)d_in[0];
    const float* wk   = (const float*)d_in[1];
    const float* bias = (const float*)d_in[2];
    float* out = (float*)d_out;

    const int T = in_sizes[0] / HDIM;    // 16384

    char* ws   = (char*)d_ws;
    int*  cnt  = (int*)(ws + WS_CNT_OFF);
    int*  list = (int*)(ws + WS_LIST_OFF);
    char* khi  = ws + WS_KHI_OFF;
    char* klo  = ws + WS_KLO_OFF;

    hipLaunchKernelGGL(moe_prep, dim3(NCH), dim3(256), 0, stream, wk, khi, klo, cnt);
    hipLaunchKernelGGL(moe_main, dim3(T / BM), dim3(THREADS), 0, stream,
                       x, khi, klo, bias, out, cnt, list, T);
    hipLaunchKernelGGL(moe_refine, dim3(256), dim3(256), 0, stream,
                       x, wk, bias, out, cnt, list, T);
}

// Round 3
// 1012.687 us; speedup vs baseline: 3.2000x; 1.6220x over previous
//
#include <hip/hip_runtime.h>
#include <math.h>

#define HDIM   7168
#define NEXP   256
#define NGROUP 8
#define EPG    32
#define TOPKG  4
#define TOPK   8
#define RSF    2.5

#define BM     64
#define BK     64
#define NCH    (HDIM / BK)      // 112
#define THREADS 512

#define TAU    6e-7f            // expert-margin refine threshold
#define TAUG   1.2e-6f          // group-margin refine threshold

typedef _Float16 f16x8 __attribute__((ext_vector_type(8)));
typedef float    f32x16 __attribute__((ext_vector_type(16)));

// ws layout (bytes):
//   [0]        int refine counter
//   [256]      int refine token list (16384 entries, 64 KB)
//   [66048]    khi image, 112 chunks x 32768 B  (f16, [chunk][col][u^swz][8])
//   [3736064]  klo image, same size
#define WS_CNT_OFF  0
#define WS_LIST_OFF 256
#define WS_KHI_OFF  66048
#define WS_KLO_OFF  (66048 + 3670016)

__device__ __forceinline__ void gload_lds16(const void* g, void* l) {
    __builtin_amdgcn_global_load_lds(
        (const __attribute__((address_space(1))) unsigned int*)g,
        (__attribute__((address_space(3))) unsigned int*)(unsigned long long)(uintptr_t)l,
        16, 0, 0);
}

// ---------------- prep: split+transpose+swizzle gate matrix, zero counter ---
__global__ __launch_bounds__(256) void moe_prep(
    const float* __restrict__ wk, char* __restrict__ khi, char* __restrict__ klo,
    int* __restrict__ cnt)
{
    if (blockIdx.x == 0 && threadIdx.x == 0) *cnt = 0;
    const int c   = blockIdx.x;    // chunk 0..111
    const int col = threadIdx.x;   // 0..255
    const long cb = (long)c * 32768 + (long)col * 128;
#pragma unroll
    for (int u = 0; u < 8; ++u) {
        f16x8 h8, l8;
#pragma unroll
        for (int i = 0; i < 8; ++i) {
            float v = wk[(long)(c * 64 + u * 8 + i) * NEXP + col];
            _Float16 h = (_Float16)v;
            float r = (v - (float)h) * 2048.0f;
            h8[i] = h;
            l8[i] = (_Float16)r;
        }
        const int uo = (u ^ (col & 7)) << 4;
        *(f16x8*)(khi + cb + uo) = h8;
        *(f16x8*)(klo + cb + uo) = l8;
    }
}

// ---------------- main: split-f16 MFMA GEMM + fused gating ------------------
// LDS: Bbuf[2] 64 KB each (hi 32K + lo 32K), xbuf[2] 16 KB each = 160 KB exact.
__global__ __launch_bounds__(THREADS, 1) void moe_main(
    const float* __restrict__ x, const char* __restrict__ khi,
    const char* __restrict__ klo, const float* __restrict__ bias,
    float* __restrict__ out, int* __restrict__ cnt, int* __restrict__ list, int T)
{
    __shared__ __align__(16) char smem[163840];

    const int tid  = threadIdx.x;
    const int w    = tid >> 6;
    const int l    = tid & 63;
    const int l31  = l & 31;
    const int half = l >> 5;
    const int e7   = l31 & 7;
    const int mg   = w & 1;          // M wave group (rows mg*32..)
    const int ng   = w >> 1;         // N wave group (cols ng*64..)
    const long t0  = (long)blockIdx.x * BM;

    // x staging assignment: thread -> (row, 8-float k segment)
    const int srow = tid >> 3;           // 0..63
    const int sk8  = (tid & 7) * 8;      // 0..56
    const float* xg = x + (t0 + srow) * HDIM + sk8;
    const int xoff = srow * 128 + ((((sk8 >> 3)) ^ (srow & 7)) << 4);

    f32x16 accm0, accc0, accm1, accc1;
#pragma unroll
    for (int i = 0; i < 16; ++i) { accm0[i] = 0.f; accc0[i] = 0.f; accm1[i] = 0.f; accc1[i] = 0.f; }
    double dsum0[16], dsum1[16];
#pragma unroll
    for (int i = 0; i < 16; ++i) { dsum0[i] = 0.0; dsum1[i] = 0.0; }

    const int arow_off = (mg * 32 + l31) * 128;
    const int bc0      = (ng * 64 + l31) * 128;

    // ---- prologue: stage chunk 0 into buffer 0
    {
        // B chunk 0 -> Bbuf0
#pragma unroll
        for (int j = 0; j < 4; ++j) {
            const int seg = (w * 4 + j) * 1024;
            gload_lds16(khi + seg + l * 16, smem + seg);
            gload_lds16(klo + seg + l * 16, smem + 32768 + seg);
        }
        // x chunk 0 -> xbuf0
        float4 p0 = *(const float4*)(xg);
        float4 p1 = *(const float4*)(xg + 4);
        float vv[8] = {p0.x, p0.y, p0.z, p0.w, p1.x, p1.y, p1.z, p1.w};
        f16x8 h8, l8;
#pragma unroll
        for (int i = 0; i < 8; ++i) {
            _Float16 h = (_Float16)vv[i];
            h8[i] = h;
            l8[i] = (_Float16)((vv[i] - (float)h) * 2048.0f);
        }
        *(f16x8*)(smem + 131072 + xoff) = h8;
        *(f16x8*)(smem + 131072 + 8192 + xoff) = l8;
    }
    __syncthreads();   // chunk 0 fully staged

    for (int c = 0; c < NCH; ++c) {
        const int p = c & 1;
        char* bb = smem + p * 65536;
        char* xb = smem + 131072 + p * 16384;
        char* bbn = smem + (p ^ 1) * 65536;
        char* xbn = smem + 131072 + (p ^ 1) * 16384;
        const bool pf = (c + 1 < NCH);

        // prefetch next chunk: x first (so its waitcnt doesn't drain B),
        // then async B loads into the alternate buffer.
        float4 p0, p1;
        if (pf) {
            const float* xp = xg + (long)(c + 1) * BK;
            p0 = *(const float4*)(xp);
            p1 = *(const float4*)(xp + 4);
            const long cb = (long)(c + 1) * 32768;
#pragma unroll
            for (int j = 0; j < 4; ++j) {
                const int seg = (w * 4 + j) * 1024;
                gload_lds16(khi + cb + seg + l * 16, bbn + seg);
                gload_lds16(klo + cb + seg + l * 16, bbn + 32768 + seg);
            }
        }

        // compute on chunk c
#pragma unroll
        for (int s = 0; s < 4; ++s) {
            const int uo = (((s * 2 + half) ^ e7) << 4);
            f16x8 ah  = *(const f16x8*)(xb + arow_off + uo);
            f16x8 al  = *(const f16x8*)(xb + 8192 + arow_off + uo);
            f16x8 bh0 = *(const f16x8*)(bb + bc0 + uo);
            f16x8 bl0 = *(const f16x8*)(bb + 32768 + bc0 + uo);
            f16x8 bh1 = *(const f16x8*)(bb + bc0 + 4096 + uo);
            f16x8 bl1 = *(const f16x8*)(bb + 32768 + bc0 + 4096 + uo);
            accm0 = __builtin_amdgcn_mfma_f32_32x32x16_f16(ah, bh0, accm0, 0, 0, 0);
            accc0 = __builtin_amdgcn_mfma_f32_32x32x16_f16(ah, bl0, accc0, 0, 0, 0);
            accm1 = __builtin_amdgcn_mfma_f32_32x32x16_f16(ah, bh1, accm1, 0, 0, 0);
            accc1 = __builtin_amdgcn_mfma_f32_32x32x16_f16(ah, bl1, accc1, 0, 0, 0);
            accc0 = __builtin_amdgcn_mfma_f32_32x32x16_f16(al, bh0, accc0, 0, 0, 0);
            accc1 = __builtin_amdgcn_mfma_f32_32x32x16_f16(al, bh1, accc1, 0, 0, 0);
        }

        // drain fp32 hi-accumulators into fp64 every 4 chunks (kills the
        // 448-step fp32 accumulation random walk; logit sigma ~8e-8)
        if ((c & 3) == 3) {
#pragma unroll
            for (int i = 0; i < 16; ++i) {
                dsum0[i] += (double)accm0[i]; accm0[i] = 0.f;
                dsum1[i] += (double)accm1[i]; accm1[i] = 0.f;
            }
        }

        // convert + write next x chunk (waits only the x float4 loads)
        if (pf) {
            float vv[8] = {p0.x, p0.y, p0.z, p0.w, p1.x, p1.y, p1.z, p1.w};
            f16x8 h8, l8;
#pragma unroll
            for (int i = 0; i < 8; ++i) {
                _Float16 h = (_Float16)vv[i];
                h8[i] = h;
                l8[i] = (_Float16)((vv[i] - (float)h) * 2048.0f);
            }
            *(f16x8*)(xbn + xoff) = h8;
            *(f16x8*)(xbn + 8192 + xoff) = l8;
        }

        __syncthreads();   // next chunk fully staged; chunk c reads done
    }

    // ---- epilogue: scores to LDS (reuse smem), fused selection
    float* sc = (float*)smem;        // [64][257] f32
    const float b0 = bias[ng * 64 + l31];
    const float b1 = bias[ng * 64 + 32 + l31];
#pragma unroll
    for (int r = 0; r < 16; ++r) {
        const int row = mg * 32 + (r & 3) + 8 * (r >> 2) + 4 * half;
        float lg0 = (float)(dsum0[r] + (double)accm0[r] + (double)accc0[r] * (1.0 / 2048.0));
        float lg1 = (float)(dsum1[r] + (double)accm1[r] + (double)accc1[r] * (1.0 / 2048.0));
        sc[row * 257 + (ng * 64 + l31)]      = 1.0f / (1.0f + expf(-lg0)) + b0;
        sc[row * 257 + (ng * 64 + 32 + l31)] = 1.0f / (1.0f + expf(-lg1)) + b1;
    }
    __syncthreads();

    if (tid < BM) {
        float* row = sc + tid * 257;

        float gsum[NGROUP];
#pragma unroll
        for (int g = 0; g < NGROUP; ++g) {
            float m1 = -1e30f, m2 = -1e30f;
            for (int j = 0; j < EPG; ++j) {
                float v = row[g * EPG + j];
                if (v > m1) { m2 = m1; m1 = v; }
                else if (v > m2) { m2 = v; }
            }
            gsum[g] = m1 + m2;
        }

        bool gsel[NGROUP];
#pragma unroll
        for (int g = 0; g < NGROUP; ++g) gsel[g] = false;
        float g4 = 0.0f;
        for (int r = 0; r < TOPKG; ++r) {
            float best = -1e30f; int bi = 0;
            for (int g = 0; g < NGROUP; ++g)
                if (!gsel[g] && gsum[g] > best) { best = gsum[g]; bi = g; }
            gsel[bi] = true; g4 = best;
        }
        float g5 = -1e30f;
        for (int g = 0; g < NGROUP; ++g)
            if (!gsel[g] && gsum[g] > g5) g5 = gsum[g];
        const float margin_g = g4 - g5;

        for (int e = 0; e < NEXP; ++e)
            if (!gsel[e >> 5]) row[e] = 0.0f;

        int   id[TOPK];
        float wv[TOPK];
        float wsum = 0.0f;
        for (int r = 0; r < TOPK; ++r) {
            float best = -1e30f; int bi = 0;
            for (int e = 0; e < NEXP; ++e) {
                float v = row[e];
                if (v > best) { best = v; bi = e; }
            }
            row[bi] = -1e30f;
            id[r] = bi; wv[r] = best; wsum += best;
        }
        float s9 = -1e30f;
        for (int e = 0; e < NEXP; ++e)
            if (row[e] > s9) s9 = row[e];

        float mmin = wv[TOPK - 1] - s9;
#pragma unroll
        for (int r = 0; r < TOPK - 1; ++r) {
            float d = wv[r] - wv[r + 1];
            if (d < mmin) mmin = d;
        }

        const float inv = 2.5f / (wsum + 1e-20f);
        const long base  = (t0 + tid) * TOPK;
        const long wbase = (long)T * TOPK + base;
#pragma unroll
        for (int r = 0; r < TOPK; ++r) {
            out[base + r]  = (float)id[r];
            out[wbase + r] = wv[r] * inv;
        }

        if (mmin < TAU || margin_g < TAUG) {
            int p2 = atomicAdd(cnt, 1);
            if (p2 < T) list[p2] = (int)(t0 + tid);
        }
    }
}

// ---------------- refine: exact fp64 recompute, k-parallel ------------------
// 1024 threads = 256 experts x 4 k-slices; one token per block (grid-stride).
__global__ __launch_bounds__(1024) void moe_refine(
    const float* __restrict__ x, const float* __restrict__ wk,
    const float* __restrict__ bias, float* __restrict__ out,
    const int* __restrict__ cnt, const int* __restrict__ list, int T)
{
    __shared__ double sp[4][NEXP];   // partials, 8 KB
    __shared__ double sd[NEXP];      // scores,   2 KB
    int n = *cnt;
    if (n > T) n = T;
    const int e = threadIdx.x & 255;
    const int q = threadIdx.x >> 8;

    for (int i = blockIdx.x; i < n; i += gridDim.x) {
        const int t = list[i];
        const float* xr = x + (long)t * HDIM + q * 1792;
        const float* wp = wk + (long)(q * 1792) * NEXP + e;
        double a0 = 0.0, a1 = 0.0;
        for (int k = 0; k < 1792; k += 2) {
            a0 = fma((double)xr[k],     (double)wp[(long)k * NEXP],       a0);
            a1 = fma((double)xr[k + 1], (double)wp[(long)(k + 1) * NEXP], a1);
        }
        sp[q][e] = a0 + a1;
        __syncthreads();

        if (q == 0) {
            double lg = sp[0][e] + sp[1][e] + sp[2][e] + sp[3][e];
            sd[e] = 1.0 / (1.0 + exp(-lg)) + (double)bias[e];
        }
        __syncthreads();

        if (threadIdx.x == 0) {
            double gsum[NGROUP];
            for (int g = 0; g < NGROUP; ++g) {
                double m1 = -1e300, m2 = -1e300;
                for (int j = 0; j < EPG; ++j) {
                    double v = sd[g * EPG + j];
                    if (v > m1) { m2 = m1; m1 = v; }
                    else if (v > m2) { m2 = v; }
                }
                gsum[g] = m1 + m2;
            }
            bool gsel[NGROUP];
            for (int g = 0; g < NGROUP; ++g) gsel[g] = false;
            for (int r = 0; r < TOPKG; ++r) {
                double best = -1e300; int bi = 0;
                for (int g = 0; g < NGROUP; ++g)
                    if (!gsel[g] && gsum[g] > best) { best = gsum[g]; bi = g; }
                gsel[bi] = true;
            }
            for (int e2 = 0; e2 < NEXP; ++e2)
                if (!gsel[e2 >> 5]) sd[e2] = 0.0;

            int id[TOPK]; double wv[TOPK]; double wsum = 0.0;
            for (int r = 0; r < TOPK; ++r) {
                double best = -1e300; int bi = 0;
                for (int e2 = 0; e2 < NEXP; ++e2) {
                    double v = sd[e2];
                    if (v > best) { best = v; bi = e2; }
                }
                sd[bi] = -1e300;
                id[r] = bi; wv[r] = best; wsum += best;
            }
            const double inv = RSF / (wsum + 1e-20);
            const long base  = (long)t * TOPK;
            const long wbase = (long)T * TOPK + base;
            for (int r = 0; r < TOPK; ++r) {
                out[base + r]  = (float)id[r];
                out[wbase + r] = (float)(wv[r] * inv);
            }
        }
        __syncthreads();
    }
}

extern "C" void kernel_launch(void* const* d_in, const int* in_sizes, int n_in,
                              void* d_out, int out_size, void* d_ws, size_t ws_size,
                              hipStream_t stream) {
    const float* x    = (const float*)d_in[0];
    const float* wk   = (const float*)d_in[1];
    const float* bias = (const float*)d_in[2];
    float* out = (float*)d_out;

    const int T = in_sizes[0] / HDIM;    // 16384

    char* ws   = (char*)d_ws;
    int*  cnt  = (int*)(ws + WS_CNT_OFF);
    int*  list = (int*)(ws + WS_LIST_OFF);
    char* khi  = ws + WS_KHI_OFF;
    char* klo  = ws + WS_KLO_OFF;

    hipLaunchKernelGGL(moe_prep, dim3(NCH), dim3(256), 0, stream, wk, khi, klo, cnt);
    hipLaunchKernelGGL(moe_main, dim3(T / BM), dim3(THREADS), 0, stream,
                       x, khi, klo, bias, out, cnt, list, T);
    hipLaunchKernelGGL(moe_refine, dim3(256), dim3(1024), 0, stream,
                       x, wk, bias, out, cnt, list, T);
}

// Round 4
// 934.251 us; speedup vs baseline: 3.4687x; 1.0840x over previous
//
#include <hip/hip_runtime.h>
#include <math.h>

#define HDIM   7168
#define NEXP   256
#define NGROUP 8
#define EPG    32
#define TOPKG  4
#define TOPK   8
#define RSF    2.5

#define BK     32
#define KHALF  3584
#define NCH    112          // chunks of 32 k per K-half
#define NB_REF 512          // refine fast-path token cap

#define TAU    6e-7f
#define TAUG   1.2e-6f

typedef _Float16 f16x8 __attribute__((ext_vector_type(8)));
typedef _Float16 f16x2 __attribute__((ext_vector_type(2)));
typedef float    f32x16 __attribute__((ext_vector_type(16)));

// ws layout (bytes):
//   0        cnt (int)
//   256      list (16384 int, 64 KB)
//   66048    khi image: 224 chunks x 16384 B   ([c][u(4)][col(256)][8 f16])
//   3736064  klo image: same
//   7406080  shared 33.55 MB: fp32 partial logits [kh][T][256]  (main->gate)
//            then ALIASED as fp64 refine partials [j<512][kc(32)][256] (A->B)
#define WS_CNT_OFF   0
#define WS_LIST_OFF  256
#define WS_KHI_OFF   66048
#define WS_KLO_OFF   3736064
#define WS_BUF_OFF   7406080
#define WS_NEED      (7406080ULL + 33554432ULL)

__device__ __forceinline__ void gload_lds16(const void* g, void* l) {
    __builtin_amdgcn_global_load_lds(
        (const __attribute__((address_space(1))) unsigned int*)g,
        (__attribute__((address_space(3))) unsigned int*)(unsigned long long)(uintptr_t)l,
        16, 0, 0);
}

// ---------------- prep: split + relayout gate matrix, zero counter ----------
__global__ __launch_bounds__(256) void moe_prep(
    const float* __restrict__ wk, char* __restrict__ khi, char* __restrict__ klo,
    int* __restrict__ cnt)
{
    if (blockIdx.x == 0 && threadIdx.x == 0) *cnt = 0;
    const int c   = blockIdx.x;    // global 32-k chunk 0..223
    const int col = threadIdx.x;
    const long cb = (long)c * 16384 + (long)col * 16;
#pragma unroll
    for (int u = 0; u < 4; ++u) {
        f16x8 h8, l8;
#pragma unroll
        for (int h = 0; h < 8; ++h) {
            float v = wk[(long)(c * 32 + u * 8 + h) * NEXP + col];
            _Float16 hi = (_Float16)v;
            h8[h] = hi;
            l8[h] = (_Float16)((v - (float)hi) * 2048.0f);
        }
        *(f16x8*)(khi + cb + u * 4096) = h8;
        *(f16x8*)(klo + cb + u * 4096) = l8;
    }
}

// ---------------- main: split-K split-f16 MFMA GEMM -> fp32 partial logits --
// grid 512 = 256 token-groups x 2 K-halves; khalf pinned per-XCD (bid%8<4)
// so each XCD's L2 only ever holds its own 3.65 MB B-half.
// LDS 80 KB: per buffer p(2): Bhi 16K | Blo 16K | Xhi 4K | Xlo 4K.
__global__ __launch_bounds__(1024) void moe_main(
    const float* __restrict__ x, const char* __restrict__ khi,
    const char* __restrict__ klo, float* __restrict__ logits, int T)
{
    __shared__ __align__(16) char smem[81920];

    const int tid  = threadIdx.x;
    const int w    = tid >> 6;
    const int l    = tid & 63;
    const int l31  = l & 31;
    const int half = l >> 5;
    const int mg   = w & 1;          // rows mg*32..
    const int ng   = w >> 1;         // cols ng*32..
    const int bid  = blockIdx.x;
    const int xcd  = bid & 7;
    const int kh   = xcd >> 2;
    const int tg   = ((bid >> 3) << 2) | (xcd & 3);
    const long t0  = (long)tg * 64;
    const int cg0  = kh * NCH;

    // x staging: thread -> (row 0..63, float2 at k = ks*2)
    const int srow = tid >> 4;
    const int ks   = tid & 15;
    const float* xg = x + (t0 + srow) * HDIM + (long)kh * KHALF + ks * 2;
    const int xodst = (ks >> 2) * 1024 + srow * 16 + (ks & 3) * 4;

    f32x16 accm, accc;
#pragma unroll
    for (int i = 0; i < 16; ++i) { accm[i] = 0.f; accc[i] = 0.f; }
    double dsum[16];
#pragma unroll
    for (int i = 0; i < 16; ++i) dsum[i] = 0.0;

    const int arow = (mg * 32 + l31) * 16;
    const int bcol = (ng * 32 + l31) * 16;

    // prologue: stage chunk 0 into buffer 0
    {
        const long cb = (long)cg0 * 16384;
        gload_lds16(khi + cb + w * 1024 + l * 16, smem + w * 1024);
        gload_lds16(klo + cb + w * 1024 + l * 16, smem + 16384 + w * 1024);
        float2 v = *(const float2*)(xg);
        _Float16 h0 = (_Float16)v.x, h1 = (_Float16)v.y;
        f16x2 hh = {h0, h1};
        f16x2 ll = {(_Float16)((v.x - (float)h0) * 2048.0f),
                    (_Float16)((v.y - (float)h1) * 2048.0f)};
        *(f16x2*)(smem + 32768 + xodst) = hh;
        *(f16x2*)(smem + 36864 + xodst) = ll;
    }
    __syncthreads();

    for (int c = 0; c < NCH; ++c) {
        const int p = c & 1;
        char* bb  = smem + p * 40960;
        char* bbn = smem + (p ^ 1) * 40960;
        const bool pf = (c + 1 < NCH);

        float2 v;
        if (pf) {
            v = *(const float2*)(xg + (long)(c + 1) * BK);
            const long cb = (long)(cg0 + c + 1) * 16384;
            gload_lds16(khi + cb + w * 1024 + l * 16, bbn + w * 1024);
            gload_lds16(klo + cb + w * 1024 + l * 16, bbn + 16384 + w * 1024);
        }

#pragma unroll
        for (int s = 0; s < 2; ++s) {
            const int u = s * 2 + half;
            f16x8 ah = *(const f16x8*)(bb + 32768 + u * 1024 + arow);
            f16x8 al = *(const f16x8*)(bb + 36864 + u * 1024 + arow);
            f16x8 bh = *(const f16x8*)(bb + u * 4096 + bcol);
            f16x8 bl = *(const f16x8*)(bb + 16384 + u * 4096 + bcol);
            accm = __builtin_amdgcn_mfma_f32_32x32x16_f16(ah, bh, accm, 0, 0, 0);
            accc = __builtin_amdgcn_mfma_f32_32x32x16_f16(ah, bl, accc, 0, 0, 0);
            accc = __builtin_amdgcn_mfma_f32_32x32x16_f16(al, bh, accc, 0, 0, 0);
        }

        if ((c & 3) == 3) {          // drain fp32 hi-acc into fp64
#pragma unroll
            for (int i = 0; i < 16; ++i) { dsum[i] += (double)accm[i]; accm[i] = 0.f; }
        }

        if (pf) {
            _Float16 h0 = (_Float16)v.x, h1 = (_Float16)v.y;
            f16x2 hh = {h0, h1};
            f16x2 ll = {(_Float16)((v.x - (float)h0) * 2048.0f),
                        (_Float16)((v.y - (float)h1) * 2048.0f)};
            *(f16x2*)(bbn + 32768 + xodst) = hh;
            *(f16x2*)(bbn + 36864 + xodst) = ll;
        }
        __syncthreads();
    }

    // epilogue: fp32 half-logits to ws (C layout: col=lane&31, row=(r&3)+8*(r>>2)+4*half)
    float* lg = logits + (long)kh * T * NEXP;
#pragma unroll
    for (int r = 0; r < 16; ++r) {
        const int lrow = (r & 3) + 8 * (r >> 2) + 4 * half;
        const long tok = t0 + mg * 32 + lrow;
        lg[tok * NEXP + ng * 32 + l31] =
            (float)(dsum[r] + (double)accm[r] + (double)accc[r] * (1.0 / 2048.0));
    }
}

// ---------------- gate: reduce halves, sigmoid+bias, grouped top-k, flags ---
__global__ __launch_bounds__(256) void moe_gate(
    const float* __restrict__ logits, const float* __restrict__ bias,
    float* __restrict__ out, int* __restrict__ cnt, int* __restrict__ list, int T)
{
    __shared__ float sc[64 * 257];
    const int e  = threadIdx.x;
    const long t0 = (long)blockIdx.x * 64;
    const float b = bias[e];
    const float* l0 = logits + t0 * NEXP + e;
    const float* l1 = logits + (long)T * NEXP + t0 * NEXP + e;
    for (int tt = 0; tt < 64; ++tt) {
        float lg = l0[tt * NEXP] + l1[tt * NEXP];
        sc[tt * 257 + e] = 1.0f / (1.0f + expf(-lg)) + b;
    }
    __syncthreads();

    if (e < 64) {
        float* row = sc + e * 257;

        float gsum[NGROUP];
#pragma unroll
        for (int g = 0; g < NGROUP; ++g) {
            float m1 = -1e30f, m2 = -1e30f;
            for (int j = 0; j < EPG; ++j) {
                float v = row[g * EPG + j];
                if (v > m1) { m2 = m1; m1 = v; }
                else if (v > m2) { m2 = v; }
            }
            gsum[g] = m1 + m2;
        }

        bool gsel[NGROUP];
#pragma unroll
        for (int g = 0; g < NGROUP; ++g) gsel[g] = false;
        float g4 = 0.0f;
        for (int r = 0; r < TOPKG; ++r) {
            float best = -1e30f; int bi = 0;
            for (int g = 0; g < NGROUP; ++g)
                if (!gsel[g] && gsum[g] > best) { best = gsum[g]; bi = g; }
            gsel[bi] = true; g4 = best;
        }
        float g5 = -1e30f;
        for (int g = 0; g < NGROUP; ++g)
            if (!gsel[g] && gsum[g] > g5) g5 = gsum[g];
        const float margin_g = g4 - g5;

        for (int e2 = 0; e2 < NEXP; ++e2)
            if (!gsel[e2 >> 5]) row[e2] = 0.0f;

        int   id[TOPK];
        float wv[TOPK];
        float wsum = 0.0f;
        for (int r = 0; r < TOPK; ++r) {
            float best = -1e30f; int bi = 0;
            for (int e2 = 0; e2 < NEXP; ++e2) {
                float v = row[e2];
                if (v > best) { best = v; bi = e2; }
            }
            row[bi] = -1e30f;
            id[r] = bi; wv[r] = best; wsum += best;
        }
        float s9 = -1e30f;
        for (int e2 = 0; e2 < NEXP; ++e2)
            if (row[e2] > s9) s9 = row[e2];

        float mmin = wv[TOPK - 1] - s9;
#pragma unroll
        for (int r = 0; r < TOPK - 1; ++r) {
            float d = wv[r] - wv[r + 1];
            if (d < mmin) mmin = d;
        }

        const float inv = 2.5f / (wsum + 1e-20f);
        const long base  = (t0 + e) * TOPK;
        const long wbase = (long)T * TOPK + base;
#pragma unroll
        for (int r = 0; r < TOPK; ++r) {
            out[base + r]  = (float)id[r];
            out[wbase + r] = wv[r] * inv;
        }

        if (mmin < TAU || margin_g < TAUG) {
            int p2 = atomicAdd(cnt, 1);
            if (p2 < T) list[p2] = (int)(t0 + e);
        }
    }
}

// ---------------- shared f64 selection ----------------
__device__ void select_f64(double* sd, int t, float* out, int T) {
    double gsum[NGROUP];
    for (int g = 0; g < NGROUP; ++g) {
        double m1 = -1e300, m2 = -1e300;
        for (int j = 0; j < EPG; ++j) {
            double v = sd[g * EPG + j];
            if (v > m1) { m2 = m1; m1 = v; }
            else if (v > m2) { m2 = v; }
        }
        gsum[g] = m1 + m2;
    }
    bool gsel[NGROUP];
    for (int g = 0; g < NGROUP; ++g) gsel[g] = false;
    for (int r = 0; r < TOPKG; ++r) {
        double best = -1e300; int bi = 0;
        for (int g = 0; g < NGROUP; ++g)
            if (!gsel[g] && gsum[g] > best) { best = gsum[g]; bi = g; }
        gsel[bi] = true;
    }
    for (int e2 = 0; e2 < NEXP; ++e2)
        if (!gsel[e2 >> 5]) sd[e2] = 0.0;

    int id[TOPK]; double wv[TOPK]; double wsum = 0.0;
    for (int r = 0; r < TOPK; ++r) {
        double best = -1e300; int bi = 0;
        for (int e2 = 0; e2 < NEXP; ++e2) {
            double v = sd[e2];
            if (v > best) { best = v; bi = e2; }
        }
        sd[bi] = -1e300;
        id[r] = bi; wv[r] = best; wsum += best;
    }
    const double inv = RSF / (wsum + 1e-20);
    const long base  = (long)t * TOPK;
    const long wbase = (long)T * TOPK + base;
    for (int r = 0; r < TOPK; ++r) {
        out[base + r]  = (float)id[r];
        out[wbase + r] = (float)(wv[r] * inv);
    }
}

// ---------------- refine stage A: fp64 partials, wk read ~once --------------
// grid 256 = 32 k-chunks x 8 token-sets; partials [j][kc][256] fp64.
__global__ __launch_bounds__(256) void moe_refineA(
    const float* __restrict__ x, const float* __restrict__ wk,
    double* __restrict__ pref, const int* __restrict__ cnt,
    const int* __restrict__ list, int T)
{
    __shared__ float xb[8][224];
    int n = *cnt; if (n > T) n = T;
    int nb = n < NB_REF ? n : NB_REF;
    const int kc = blockIdx.x >> 3;
    const int tg = blockIdx.x & 7;
    const int e  = threadIdx.x;

    for (int jb = tg; jb < nb; jb += 64) {
        for (int i = 0; i < 8; ++i) {
            int j = jb + 8 * i;
            if (j >= nb) break;
            if (e < 56) {
                const float* xp = x + (long)list[j] * HDIM + kc * 224 + e * 4;
                *(float4*)&xb[i][e * 4] = *(const float4*)xp;
            }
        }
        __syncthreads();

        double acc[8];
#pragma unroll
        for (int i = 0; i < 8; ++i) acc[i] = 0.0;
        const float* wp = wk + (long)(kc * 224) * NEXP + e;
#pragma unroll 4
        for (int k = 0; k < 224; ++k) {
            double wv = (double)wp[(long)k * NEXP];
#pragma unroll
            for (int i = 0; i < 8; ++i)
                acc[i] = fma((double)xb[i][k], wv, acc[i]);
        }
        for (int i = 0; i < 8; ++i) {
            int j = jb + 8 * i;
            if (j < nb) pref[((long)j * 32 + kc) * NEXP + e] = acc[i];
        }
        __syncthreads();
    }
}

// ---------------- refine stage B: reduce + exact select ---------------------
__global__ __launch_bounds__(256) void moe_refineB(
    const float* __restrict__ x, const float* __restrict__ wk,
    const float* __restrict__ bias, float* __restrict__ out,
    const double* __restrict__ pref, const int* __restrict__ cnt,
    const int* __restrict__ list, int T)
{
    __shared__ double sd[NEXP];
    int n = *cnt; if (n > T) n = T;
    int nb = n < NB_REF ? n : NB_REF;
    const int e = threadIdx.x;
    const int i = blockIdx.x;

    const int t = (i < nb) ? list[i] : -1;
    double s = 0.0;
    if (t >= 0) {
        const double* pp = pref + (long)i * 32 * NEXP + e;
#pragma unroll
        for (int kc = 0; kc < 32; ++kc) s += pp[kc * NEXP];
    }
    sd[e] = (t >= 0) ? (1.0 / (1.0 + exp(-s)) + (double)bias[e]) : 0.0;
    __syncthreads();
    if (t >= 0 && e == 0) select_f64(sd, t, out, T);
    __syncthreads();

    // overflow fallback (n > NB_REF): slow exact per-token — expected never
    for (int j = NB_REF + i; j < n; j += 512) {
        const int tt = list[j];
        const float* xr = x + (long)tt * HDIM;
        double a0 = 0.0, a1 = 0.0;
        for (int k = 0; k < HDIM; k += 2) {
            a0 = fma((double)xr[k],     (double)wk[(long)k * NEXP + e],       a0);
            a1 = fma((double)xr[k + 1], (double)wk[(long)(k + 1) * NEXP + e], a1);
        }
        sd[e] = 1.0 / (1.0 + exp(-(a0 + a1))) + (double)bias[e];
        __syncthreads();
        if (e == 0) select_f64(sd, tt, out, T);
        __syncthreads();
    }
}

// ---------------- fallback: full fp64 (used only if ws too small) -----------
__global__ __launch_bounds__(256) void moe_gate_f64_full(
    const float* __restrict__ x, const float* __restrict__ wk,
    const float* __restrict__ bias, float* __restrict__ out, int T)
{
    __shared__ double sc[16][NEXP + 1];
    const int  e  = threadIdx.x;
    const long t0 = (long)blockIdx.x * 16;
    const float* xb = x + t0 * HDIM;
    double acc[16];
#pragma unroll
    for (int t = 0; t < 16; ++t) acc[t] = 0.0;
    for (int k = 0; k < HDIM; k += 4) {
        double kv0 = (double)wk[(long)(k + 0) * NEXP + e];
        double kv1 = (double)wk[(long)(k + 1) * NEXP + e];
        double kv2 = (double)wk[(long)(k + 2) * NEXP + e];
        double kv3 = (double)wk[(long)(k + 3) * NEXP + e];
#pragma unroll
        for (int t = 0; t < 16; ++t) {
            const float* xr = xb + (long)t * HDIM + k;
            double a = acc[t];
            a = fma((double)xr[0], kv0, a);
            a = fma((double)xr[1], kv1, a);
            a = fma((double)xr[2], kv2, a);
            a = fma((double)xr[3], kv3, a);
            acc[t] = a;
        }
    }
    const double b = (double)bias[e];
#pragma unroll
    for (int t = 0; t < 16; ++t)
        sc[t][e] = 1.0 / (1.0 + exp(-acc[t])) + b;
    __syncthreads();
    if (e < 16) select_f64(&sc[e][0], (int)(t0 + e), out, T);
}

extern "C" void kernel_launch(void* const* d_in, const int* in_sizes, int n_in,
                              void* d_out, int out_size, void* d_ws, size_t ws_size,
                              hipStream_t stream) {
    const float* x    = (const float*)d_in[0];
    const float* wk   = (const float*)d_in[1];
    const float* bias = (const float*)d_in[2];
    float* out = (float*)d_out;
    const int T = in_sizes[0] / HDIM;    // 16384

    if (ws_size < WS_NEED) {   // safety net: exact fp64, no workspace needed
        hipLaunchKernelGGL(moe_gate_f64_full, dim3(T / 16), dim3(256), 0, stream,
                           x, wk, bias, out, T);
        return;
    }

    char*   ws     = (char*)d_ws;
    int*    cnt    = (int*)(ws + WS_CNT_OFF);
    int*    list   = (int*)(ws + WS_LIST_OFF);
    char*   khi    = ws + WS_KHI_OFF;
    char*   klo    = ws + WS_KLO_OFF;
    float*  logits = (float*)(ws + WS_BUF_OFF);
    double* pref   = (double*)(ws + WS_BUF_OFF);  // aliased after gate reads

    hipLaunchKernelGGL(moe_prep,    dim3(224), dim3(256),  0, stream, wk, khi, klo, cnt);
    hipLaunchKernelGGL(moe_main,    dim3(512), dim3(1024), 0, stream, x, khi, klo, logits, T);
    hipLaunchKernelGGL(moe_gate,    dim3(T / 64), dim3(256), 0, stream, logits, bias, out, cnt, list, T);
    hipLaunchKernelGGL(moe_refineA, dim3(256), dim3(256),  0, stream, x, wk, pref, cnt, list, T);
    hipLaunchKernelGGL(moe_refineB, dim3(512), dim3(256),  0, stream, x, wk, bias, out, pref, cnt, list, T);
}